// Round 3
// baseline (5764.769 us; speedup 1.0000x reference)
//
#include <hip/hip_runtime.h>
#include <hip/hip_bf16.h>
#include <math.h>

#define M_ROWS 32768
#define NE 2048
#define EDIM 128

// d_out element offsets (fp32)
#define O_LOSS 0
#define O_ZQ 1ll
#define O_PERP 4194305ll
#define O_MINENC 4194306ll
#define O_IDX 71303170ll

// ---------------- eq = ||e_n||^2, and zero the histogram ----------------
__global__ void eq_kernel(const float* __restrict__ emb, float* __restrict__ eq,
                          int* __restrict__ hist) {
    int n = blockIdx.x;            // 2048 blocks, 64 threads (1 wave)
    int lane = threadIdx.x;
    float v0 = emb[(size_t)n * EDIM + lane];
    float v1 = emb[(size_t)n * EDIM + 64 + lane];
    float s = v0 * v0 + v1 * v1;
    #pragma unroll
    for (int off = 32; off >= 1; off >>= 1) s += __shfl_down(s, off);
    if (lane == 0) { eq[n] = s; hist[n] = 0; }
}

// ---------------- fused: argmin + idx + hist + z_q_st + loss partial + minenc ----
// argmin over n of (||z_m||^2 + eq[n]) - 2*z.e[n], fp32-quantized like the reference
// (the +||z||^2 at ~128 scale quantizes d to ulp ~1.5e-5; emulating that is required
//  for tie-breaks to match numpy first-occurrence semantics).
// LDS tiles stored with 16B-chunk XOR swizzle: chunk cc of row r lives at
// cc ^ ((r>>2)&7). Inner-loop eb reads (rows 4*tc+c) then hit 8 distinct bank-quads
// with 2 addresses each -> 2-way (free) instead of 8-way with a padded layout.
__global__ __launch_bounds__(256) void vq_fused_kernel(const float* __restrict__ z,
                                                       const float* __restrict__ emb,
                                                       const float* __restrict__ eq,
                                                       float* __restrict__ out,
                                                       float* __restrict__ part,
                                                       int* __restrict__ hist) {
    __shared__ float zs[64 * 128];   // swizzled
    __shared__ float es[64 * 128];   // swizzled
    __shared__ float zsums[64];
    __shared__ int   ids[64];
    __shared__ float red[256];

    const int tid = threadIdx.x;
    const int m0 = blockIdx.x * 64;
    const int tr = tid >> 4;        // 0..15 row-group
    const int tc = tid & 15;        // 0..15 col-group

    // ---- stage z tile (global -> LDS, swizzled) ----
    #pragma unroll
    for (int j = 0; j < 8; j++) {
        int i = tid + j * 256;
        int r = i >> 5, cc = i & 31;
        float4 v = reinterpret_cast<const float4*>(z + (size_t)(m0 + r) * EDIM)[cc];
        *reinterpret_cast<float4*>(&zs[r * 128 + ((cc ^ ((r >> 2) & 7)) << 2)]) = v;
    }
    // ---- prefetch emb tile 0 into registers ----
    float4 g[8];
    #pragma unroll
    for (int j = 0; j < 8; j++) {
        int i = tid + j * 256;
        int r = i >> 5, cc = i & 31;
        g[j] = reinterpret_cast<const float4*>(emb + (size_t)r * EDIM)[cc];
    }
    __syncthreads();                 // zs visible

    // per-row ||z||^2, fp32, k-ascending order (bit-identical to a scalar k loop)
    if (tid < 64) {
        const float* zr = &zs[tid * 128];
        const int key = (tid >> 2) & 7;
        float s = 0.0f;
        #pragma unroll
        for (int cc = 0; cc < 32; cc++) {
            float4 v = *reinterpret_cast<const float4*>(zr + ((cc ^ key) << 2));
            s += v.x * v.x;
            s += v.y * v.y;
            s += v.z * v.z;
            s += v.w * v.w;
        }
        zsums[tid] = s;
    }
    // write es tile 0
    #pragma unroll
    for (int j = 0; j < 8; j++) {
        int i = tid + j * 256;
        int r = i >> 5, cc = i & 31;
        *reinterpret_cast<float4*>(&es[r * 128 + ((cc ^ ((r >> 2) & 7)) << 2)]) = g[j];
    }
    __syncthreads();                 // es + zsums visible

    float zsum_r[4];
    #pragma unroll
    for (int r = 0; r < 4; r++) zsum_r[r] = zsums[tr * 4 + r];

    float best[4];
    int   bidx[4];
    #pragma unroll
    for (int r = 0; r < 4; r++) { best[r] = 3.4e38f; bidx[r] = 0; }

    const int keyz = tr & 7;
    const int keye = tc & 7;

    for (int t = 0; t < NE / 64; t++) {
        // prefetch next emb tile (latency hides under the k-loop)
        if (t < 31) {
            #pragma unroll
            for (int j = 0; j < 8; j++) {
                int i = tid + j * 256;
                int r = i >> 5, cc = i & 31;
                g[j] = reinterpret_cast<const float4*>(emb + (size_t)((t + 1) * 64 + r) * EDIM)[cc];
            }
        }
        float eqv[4];
        #pragma unroll
        for (int c = 0; c < 4; c++) eqv[c] = eq[t * 64 + tc * 4 + c];

        float acc[4][4] = {};
        #pragma unroll
        for (int cc = 0; cc < 32; cc++) {
            const int oz = (cc ^ keyz) << 2;
            const int oe = (cc ^ keye) << 2;
            float4 za[4], eb[4];
            #pragma unroll
            for (int r = 0; r < 4; r++)
                za[r] = *reinterpret_cast<const float4*>(&zs[(tr * 4 + r) * 128 + oz]);
            #pragma unroll
            for (int c = 0; c < 4; c++)
                eb[c] = *reinterpret_cast<const float4*>(&es[(tc * 4 + c) * 128 + oe]);
            #pragma unroll
            for (int r = 0; r < 4; r++)
                #pragma unroll
                for (int c = 0; c < 4; c++)
                    acc[r][c] += za[r].x * eb[c].x + za[r].y * eb[c].y
                               + za[r].z * eb[c].z + za[r].w * eb[c].w;
        }

        #pragma unroll
        for (int c = 0; c < 4; c++) {       // increasing n; strict < keeps earliest
            int n = t * 64 + tc * 4 + c;
            #pragma unroll
            for (int r = 0; r < 4; r++) {
                float zse = zsum_r[r] + eqv[c];   // fp32 round at ~128 scale
                float val = zse - 2.0f * acc[r][c];
                if (val < best[r]) { best[r] = val; bidx[r] = n; }
            }
        }

        __syncthreads();             // all readers done with es
        if (t < 31) {
            #pragma unroll
            for (int j = 0; j < 8; j++) {
                int i = tid + j * 256;
                int r = i >> 5, cc = i & 31;
                *reinterpret_cast<float4*>(&es[r * 128 + ((cc ^ ((r >> 2) & 7)) << 2)]) = g[j];
            }
            __syncthreads();         // es tile t+1 ready
        }
    }

    // reduce across the 16 tc-threads (offs 8,4,2,1 stay within the 16-lane group)
    #pragma unroll
    for (int off = 8; off >= 1; off >>= 1) {
        #pragma unroll
        for (int r = 0; r < 4; r++) {
            float ov = __shfl_xor(best[r], off);
            int   oi = __shfl_xor(bidx[r], off);
            if (ov < best[r] || (ov == best[r] && oi < bidx[r])) {
                best[r] = ov; bidx[r] = oi;
            }
        }
    }
    if (tc == 0) {
        #pragma unroll
        for (int r = 0; r < 4; r++) ids[tr * 4 + r] = bidx[r];
    }
    __syncthreads();                 // ids visible

    // ---- idx (fp32) + histogram ----
    if (tid < 64) {
        int id = ids[tid];
        out[O_IDX + m0 + tid] = (float)id;
        atomicAdd(&hist[id], 1);
    }

    // ---- z_q_st + loss partial ----
    float s = 0.0f;
    #pragma unroll
    for (int j = 0; j < 8; j++) {
        int i = tid + j * 256;
        int r = i >> 5, cc = i & 31;
        int id = ids[r];
        float4 e = reinterpret_cast<const float4*>(emb + (size_t)id * EDIM)[cc];
        float4 zv = *reinterpret_cast<const float4*>(&zs[r * 128 + ((cc ^ ((r >> 2) & 7)) << 2)]);
        float dx = e.x - zv.x, dy = e.y - zv.y, dz = e.z - zv.z, dw = e.w - zv.w;
        float* o = out + O_ZQ + (size_t)(m0 + r) * EDIM + cc * 4;   // 4B-aligned region
        o[0] = zv.x + dx; o[1] = zv.y + dy; o[2] = zv.z + dz; o[3] = zv.w + dw;
        s += dx * dx; s += dy * dy; s += dz * dz; s += dw * dw;
    }
    red[tid] = s;
    __syncthreads();
    #pragma unroll
    for (int o = 128; o >= 1; o >>= 1) {
        if (tid < o) red[tid] += red[tid + o];
        __syncthreads();
    }
    if (tid == 0) part[blockIdx.x] = red[0];

    // ---- min_encodings one-hot (float2: region is only 8B-aligned) ----
    float2* me2 = reinterpret_cast<float2*>(out + O_MINENC + (size_t)m0 * NE);
    for (int r = 0; r < 64; r++) {
        int id = ids[r];             // uniform broadcast
        #pragma unroll
        for (int jj = 0; jj < 4; jj++) {
            int c2 = jj * 256 + tid;
            int col = c2 << 1;
            float2 v;
            v.x = (col == id) ? 1.0f : 0.0f;
            v.y = (col + 1 == id) ? 1.0f : 0.0f;
            me2[r * 1024 + c2] = v;
        }
    }
}

// ---------------- finalize: loss + perplexity (deterministic fixed-order) ----------
__global__ __launch_bounds__(256) void finalize_kernel(const float* __restrict__ part,
                                                       const int* __restrict__ hist,
                                                       float* __restrict__ out) {
    __shared__ float red[256];
    const int tid = threadIdx.x;
    float s = part[tid] + part[tid + 256];       // 512 block partials
    red[tid] = s;
    __syncthreads();
    #pragma unroll
    for (int o = 128; o >= 1; o >>= 1) {
        if (tid < o) red[tid] += red[tid + o];
        __syncthreads();
    }
    if (tid == 0) out[O_LOSS] = 1.25f * red[0] / (float)((size_t)M_ROWS * EDIM);
    __syncthreads();

    float h = 0.0f;
    for (int i = 0; i < 8; i++) {
        float p = (float)hist[tid * 8 + i] * (1.0f / (float)M_ROWS);
        h += p * logf(p + 1e-10f);
    }
    red[tid] = h;
    __syncthreads();
    #pragma unroll
    for (int o = 128; o >= 1; o >>= 1) {
        if (tid < o) red[tid] += red[tid + o];
        __syncthreads();
    }
    if (tid == 0) out[O_PERP] = expf(-red[0]);
}

extern "C" void kernel_launch(void* const* d_in, const int* in_sizes, int n_in,
                              void* d_out, int out_size, void* d_ws, size_t ws_size,
                              hipStream_t stream) {
    const float* z   = (const float*)d_in[0];
    const float* emb = (const float*)d_in[1];
    float* out = (float*)d_out;

    char* ws = (char*)d_ws;
    float* eq   = (float*)ws;                    // 2048 f32
    int*   hist = (int*)(ws + 8192);             // 2048 i32
    float* part = (float*)(ws + 16384);          // 512 f32

    eq_kernel<<<NE, 64, 0, stream>>>(emb, eq, hist);
    vq_fused_kernel<<<M_ROWS / 64, 256, 0, stream>>>(z, emb, eq, out, part, hist);
    finalize_kernel<<<1, 256, 0, stream>>>(part, hist, out);
}

// Round 4
// 364.986 us; speedup vs baseline: 15.7945x; 15.7945x over previous
//
#include <hip/hip_runtime.h>
#include <hip/hip_bf16.h>
#include <math.h>

#define M_ROWS 32768
#define NE 2048
#define EDIM 128

// d_out element offsets (fp32)
#define O_LOSS 0
#define O_ZQ 1
#define O_PERP 4194305
#define O_MINENC 4194306
#define O_IDX 71303170ll

// ---------------- eq = ||e_n||^2, and zero the histogram ----------------
__global__ void eq_kernel(const float* __restrict__ emb, float* __restrict__ eq,
                          int* __restrict__ hist) {
    int n = blockIdx.x;            // 2048 blocks, 64 threads (1 wave)
    int lane = threadIdx.x;
    float v0 = emb[(size_t)n * EDIM + lane];
    float v1 = emb[(size_t)n * EDIM + 64 + lane];
    float s = v0 * v0 + v1 * v1;
    #pragma unroll
    for (int off = 32; off >= 1; off >>= 1) s += __shfl_down(s, off);
    if (lane == 0) { eq[n] = s; hist[n] = 0; }
}

// ---------------- argmin over n of (||z_m||^2 + eq[n]) - 2*z.e[n] ----------------
// fp32-quantized exactly like the reference (the +||z||^2 at ~128 scale quantizes d
// to ulp ~1.5e-5; emulating that is required for numpy-matching tie-breaks).
// LDS layout: 16B chunk cc of row r stored at physical chunk (cc ^ ((r>>2)&7)).
//  - eb reads (rows 4*tc+c, fixed chunk): bank-quad = cc^(tc&7) -> 8 quads x 2 addrs
//    = 2-way (free, m136) instead of 8-way with the old padded layout.
//  - za reads: 4 distinct quads, 16-lane broadcast, conflict-free.
// Structure is the round-2 one (88 VGPR, no reg prefetch, no unroll pragma): the
// round-3 fusion+prefetch variant spilled (VGPR 256, 12.7 GB scratch writes).
__global__ __launch_bounds__(256) void argmin_kernel(const float* __restrict__ z,
                                                     const float* __restrict__ emb,
                                                     const float* __restrict__ eq,
                                                     int* __restrict__ out_idx) {
    __shared__ float zs[64 * 128];   // swizzled
    __shared__ float es[64 * 128];   // swizzled
    __shared__ float eqs[64];
    __shared__ float zsums[64];
    const int tid = threadIdx.x;
    const int m0 = blockIdx.x * 64;
    const int tr = tid >> 4;        // 0..15 row-group
    const int tc = tid & 15;        // 0..15 col-group

    // stage z tile (64x128 floats = 2048 float4), swizzled store
    for (int i = tid; i < 2048; i += 256) {
        int r = i >> 5, cc = i & 31;
        float4 v = reinterpret_cast<const float4*>(z + (size_t)(m0 + r) * EDIM)[cc];
        *reinterpret_cast<float4*>(&zs[r * 128 + ((cc ^ ((r >> 2) & 7)) << 2)]) = v;
    }
    __syncthreads();
    // per-row ||z||^2 in fp32, k-ascending order (bit-identical to scalar loop;
    // any fp32 zsum at this scale differs from the reference's by an exact multiple
    // of the rounding grid, which shifts all candidates identically)
    if (tid < 64) {
        const float* zr = &zs[tid * 128];
        const int key = (tid >> 2) & 7;
        float s = 0.0f;
        for (int cc = 0; cc < 32; cc++) {
            float4 v = *reinterpret_cast<const float4*>(zr + ((cc ^ key) << 2));
            s += v.x * v.x;
            s += v.y * v.y;
            s += v.z * v.z;
            s += v.w * v.w;
        }
        zsums[tid] = s;
    }

    float best[4];
    int   bidx[4];
    #pragma unroll
    for (int r = 0; r < 4; r++) { best[r] = 3.4e38f; bidx[r] = 0; }

    const int keyz = tr & 7;        // storage key for rows tr*4..tr*4+3
    const int keye = tc & 7;        // storage key for rows tc*4..tc*4+3

    for (int t = 0; t < NE / 64; t++) {
        __syncthreads();   // protect es from previous iteration's readers; covers zsums at t=0
        for (int i = tid; i < 2048; i += 256) {
            int r = i >> 5, cc = i & 31;
            float4 v = reinterpret_cast<const float4*>(emb + (size_t)(t * 64 + r) * EDIM)[cc];
            *reinterpret_cast<float4*>(&es[r * 128 + ((cc ^ ((r >> 2) & 7)) << 2)]) = v;
        }
        if (tid < 64) eqs[tid] = eq[t * 64 + tid];
        __syncthreads();

        float acc[4][4] = {};
        for (int cc = 0; cc < 32; cc++) {      // logical chunk cc = k/4, ascending
            const int oz = (cc ^ keyz) << 2;
            const int oe = (cc ^ keye) << 2;
            float4 za[4], eb[4];
            #pragma unroll
            for (int r = 0; r < 4; r++)
                za[r] = *reinterpret_cast<const float4*>(&zs[(tr * 4 + r) * 128 + oz]);
            #pragma unroll
            for (int c = 0; c < 4; c++)
                eb[c] = *reinterpret_cast<const float4*>(&es[(tc * 4 + c) * 128 + oe]);
            #pragma unroll
            for (int r = 0; r < 4; r++)
                #pragma unroll
                for (int c = 0; c < 4; c++)
                    acc[r][c] += za[r].x * eb[c].x + za[r].y * eb[c].y
                               + za[r].z * eb[c].z + za[r].w * eb[c].w;
        }

        #pragma unroll
        for (int c = 0; c < 4; c++) {       // increasing n order; strict < keeps earliest
            float eqv = eqs[tc * 4 + c];
            int n = t * 64 + tc * 4 + c;
            #pragma unroll
            for (int r = 0; r < 4; r++) {
                float zse = zsums[tr * 4 + r] + eqv;   // fp32 round at ~128 scale
                float val = zse - 2.0f * acc[r][c];    // 2*acc exact, single round
                if (val < best[r]) { best[r] = val; bidx[r] = n; }
            }
        }
    }

    // reduce across the 16 threads (same tr group, lanes tc=0..15 contiguous)
    #pragma unroll
    for (int off = 8; off >= 1; off >>= 1) {
        #pragma unroll
        for (int r = 0; r < 4; r++) {
            float ov = __shfl_xor(best[r], off);
            int   oi = __shfl_xor(bidx[r], off);
            if (ov < best[r] || (ov == best[r] && oi < bidx[r])) {
                best[r] = ov; bidx[r] = oi;
            }
        }
    }
    if (tc == 0) {
        #pragma unroll
        for (int r = 0; r < 4; r++) out_idx[m0 + tr * 4 + r] = bidx[r];
    }
}

// ---------------- min_encodings one-hot fill (float2 stores; region is 8B-aligned) ----
__global__ __launch_bounds__(256) void minenc_kernel(const int* __restrict__ idx,
                                                     float* __restrict__ out /* d_out+O_MINENC */) {
    size_t i = (size_t)blockIdx.x * blockDim.x + threadIdx.x;
    const size_t total = (size_t)M_ROWS * (NE / 2);   // float2 count
    const size_t stride = (size_t)gridDim.x * blockDim.x;
    for (; i < total; i += stride) {
        int row = (int)(i >> 10);
        int col = (int)(i & 1023) << 1;
        int id = idx[row];
        float2 v;
        v.x = (col == id) ? 1.0f : 0.0f;
        v.y = (col + 1 == id) ? 1.0f : 0.0f;
        reinterpret_cast<float2*>(out)[i] = v;
    }
}

// ---------------- gather z_q, write z_q_st, idx(float), loss partials, histogram ----
__global__ __launch_bounds__(256) void gather_kernel(const float* __restrict__ z,
                                                     const float* __restrict__ emb,
                                                     const int* __restrict__ idx,
                                                     float* __restrict__ out,
                                                     float* __restrict__ partial,
                                                     int* __restrict__ hist) {
    __shared__ float red[256];
    const int tid = threadIdx.x;
    const int rl = tid >> 4;      // 16 rows per block
    const int sub = tid & 15;     // 16 threads per row, 8 elems each
    const int row = blockIdx.x * 16 + rl;
    const int id = idx[row];

    const float* zr = z + (size_t)row * EDIM + sub * 8;
    const float* er = emb + (size_t)id * EDIM + sub * 8;
    float* outr = out + O_ZQ + (size_t)row * EDIM + sub * 8;

    float4 z0 = reinterpret_cast<const float4*>(zr)[0];
    float4 z1 = reinterpret_cast<const float4*>(zr)[1];
    float4 e0 = reinterpret_cast<const float4*>(er)[0];
    float4 e1 = reinterpret_cast<const float4*>(er)[1];

    float zz[8] = {z0.x, z0.y, z0.z, z0.w, z1.x, z1.y, z1.z, z1.w};
    float ee[8] = {e0.x, e0.y, e0.z, e0.w, e1.x, e1.y, e1.z, e1.w};
    float s = 0.0f;
    #pragma unroll
    for (int j = 0; j < 8; j++) {
        float d = ee[j] - zz[j];
        outr[j] = zz[j] + d;      // match reference's z + (z_q - z) rounding
        s += d * d;
    }
    if (sub == 0) {
        atomicAdd(&hist[id], 1);
        out[O_IDX + row] = (float)id;
    }
    red[tid] = s;
    __syncthreads();
    #pragma unroll
    for (int o = 128; o >= 1; o >>= 1) {
        if (tid < o) red[tid] += red[tid + o];
        __syncthreads();
    }
    if (tid == 0) partial[blockIdx.x] = red[0];
}

// ---------------- finalize: loss + perplexity (deterministic fixed-order) ----------
__global__ __launch_bounds__(256) void finalize_kernel(const float* __restrict__ partial,
                                                       const int* __restrict__ hist,
                                                       float* __restrict__ out) {
    __shared__ float red[256];
    const int tid = threadIdx.x;
    float s = 0.0f;
    for (int i = 0; i < 8; i++) s += partial[tid * 8 + i];
    red[tid] = s;
    __syncthreads();
    #pragma unroll
    for (int o = 128; o >= 1; o >>= 1) {
        if (tid < o) red[tid] += red[tid + o];
        __syncthreads();
    }
    if (tid == 0) out[O_LOSS] = 1.25f * red[0] / (float)((size_t)M_ROWS * EDIM);
    __syncthreads();

    float h = 0.0f;
    for (int i = 0; i < 8; i++) {
        float p = (float)hist[tid * 8 + i] * (1.0f / (float)M_ROWS);
        h += p * logf(p + 1e-10f);
    }
    red[tid] = h;
    __syncthreads();
    #pragma unroll
    for (int o = 128; o >= 1; o >>= 1) {
        if (tid < o) red[tid] += red[tid + o];
        __syncthreads();
    }
    if (tid == 0) out[O_PERP] = expf(-red[0]);
}

extern "C" void kernel_launch(void* const* d_in, const int* in_sizes, int n_in,
                              void* d_out, int out_size, void* d_ws, size_t ws_size,
                              hipStream_t stream) {
    const float* z   = (const float*)d_in[0];
    const float* emb = (const float*)d_in[1];
    float* out = (float*)d_out;

    char* ws = (char*)d_ws;
    float* eq     = (float*)ws;                 // 2048 f32
    int*   idx    = (int*)(ws + 8192);          // 32768 i32
    int*   hist   = (int*)(ws + 8192 + 131072); // 2048 i32
    float* part   = (float*)(ws + 8192 + 131072 + 8192); // 2048 f32

    eq_kernel<<<NE, 64, 0, stream>>>(emb, eq, hist);
    argmin_kernel<<<M_ROWS / 64, 256, 0, stream>>>(z, emb, eq, idx);
    minenc_kernel<<<8192, 256, 0, stream>>>(idx, out + O_MINENC);
    gather_kernel<<<M_ROWS / 16, 256, 0, stream>>>(z, emb, idx, out, part, hist);
    finalize_kernel<<<1, 256, 0, stream>>>(part, hist, out);
}